// Round 1
// baseline (145.109 us; speedup 1.0000x reference)
//
#include <hip/hip_runtime.h>
#include <hip/hip_bf16.h>
#include <stdint.h>

#define SS 2048
#define DD 1024
#define RR 8192   // B*S = 4*2048

typedef _Float16 f16;
typedef _Float16 f16x8 __attribute__((ext_vector_type(8)));
typedef _Float16 f16x4 __attribute__((ext_vector_type(4)));
typedef float    f32x4 __attribute__((ext_vector_type(4)));

// ---------- K0: Wq,Wk (f32) -> Wcat f16 [2048][1024]  (row i<1024 = Wq row i, else Wk)
__global__ __launch_bounds__(256) void k_wconv(const float* __restrict__ Wq,
                                               const float* __restrict__ Wk,
                                               f16* __restrict__ Wcat) {
  int gid = blockIdx.x * 256 + threadIdx.x;   // 524288 threads
  int i = gid * 4;
  const float* src = (i < 1048576) ? (Wq + i) : (Wk + (i - 1048576));
  float4 v = *(const float4*)src;
  f16x4 o; o[0]=(f16)v.x; o[1]=(f16)v.y; o[2]=(f16)v.z; o[3]=(f16)v.w;
  *(f16x4*)(Wcat + i) = o;
}

// ---------- K1: LayerNorm rows of context -> f16 Xn [8192][1024]
__global__ __launch_bounds__(256) void k_ln(const float* __restrict__ x,
                                            const float* __restrict__ gamma,
                                            const float* __restrict__ beta,
                                            f16* __restrict__ xn) {
  int row = blockIdx.x;
  int tid = threadIdx.x;
  int lane = tid & 63, w = tid >> 6;
  const float* xr = x + (size_t)row * DD;
  float4 v = ((const float4*)xr)[tid];
  float s  = v.x + v.y + v.z + v.w;
  float ss = v.x*v.x + v.y*v.y + v.z*v.z + v.w*v.w;
#pragma unroll
  for (int off = 32; off > 0; off >>= 1) {
    s  += __shfl_down(s,  off, 64);
    ss += __shfl_down(ss, off, 64);
  }
  __shared__ float r0[4], r1[4];
  if (lane == 0) { r0[w] = s; r1[w] = ss; }
  __syncthreads();
  float tot = r0[0]+r0[1]+r0[2]+r0[3];
  float tss = r1[0]+r1[1]+r1[2]+r1[3];
  float mu  = tot * (1.0f/DD);
  float var = tss * (1.0f/DD) - mu*mu;
  float inv = rsqrtf(var + 1e-5f);
  float4 g = ((const float4*)gamma)[tid];
  float4 b = ((const float4*)beta)[tid];
  f16x4 o;
  o[0] = (f16)((v.x-mu)*inv*g.x + b.x);
  o[1] = (f16)((v.y-mu)*inv*g.y + b.y);
  o[2] = (f16)((v.z-mu)*inv*g.z + b.z);
  o[3] = (f16)((v.w-mu)*inv*g.w + b.w);
  *(f16x4*)(xn + (size_t)row*DD + tid*4) = o;
}

// ---------- K2: NT GEMM  C[8192][2048] = Xn[8192][1024] @ Wcat[2048][1024]^T   (f16 in, f32 acc, f16 out)
// 128x128 tile, BK=32, 4 waves (2x2), 4x4 16x16x32 fragments per wave.
// LDS XOR swizzle: chunk ^= (row>>1)&3   (16B chunks; makes ds_read_b128 2-way = free)
__global__ __launch_bounds__(256) void k_gemm(const f16* __restrict__ A,
                                              const f16* __restrict__ Bw,
                                              f16* __restrict__ C) {
  __shared__ f16 As[128*32];
  __shared__ f16 Bs[128*32];
  int bid = blockIdx.x;
  int bm = bid >> 4, bn = bid & 15;     // 64 x 16 blocks
  int tid = threadIdx.x;
  int lane = tid & 63;
  int w = tid >> 6, wm = w >> 1, wn = w & 1;

  f32x4 acc[4][4] = {};

  int srow   = tid >> 2;   // 0..63 (+64 second issue)
  int schunk = tid & 3;    // 16B chunk in row
  const f16* Agp = A  + (size_t)(bm*128 + srow) * DD + schunk*8;
  const f16* Bgp = Bw + (size_t)(bn*128 + srow) * DD + schunk*8;
  int sw  = (srow >> 1) & 3;                    // same for srow and srow+64
  int aw0 = srow*32 + ((schunk ^ sw) * 8);
  int aw1 = aw0 + 64*32;
  int rsw    = ((lane & 15) >> 1) & 3;          // read-side swizzle (row low bits only)
  int rchunk = ((lane >> 4) ^ rsw) * 8;
  int rlo    = lane & 15;

  for (int kt = 0; kt < DD; kt += 32) {
    f16x8 ra0 = *(const f16x8*)(Agp + kt);
    f16x8 ra1 = *(const f16x8*)(Agp + 64*DD + kt);
    f16x8 rb0 = *(const f16x8*)(Bgp + kt);
    f16x8 rb1 = *(const f16x8*)(Bgp + 64*DD + kt);
    __syncthreads();                      // previous iteration's reads done
    *(f16x8*)(As + aw0) = ra0;
    *(f16x8*)(As + aw1) = ra1;
    *(f16x8*)(Bs + aw0) = rb0;
    *(f16x8*)(Bs + aw1) = rb1;
    __syncthreads();                      // tiles visible
    f16x8 af[4], bf[4];
#pragma unroll
    for (int mi = 0; mi < 4; ++mi)
      af[mi] = *(const f16x8*)(As + (wm*64 + mi*16 + rlo)*32 + rchunk);
#pragma unroll
    for (int ni = 0; ni < 4; ++ni)
      bf[ni] = *(const f16x8*)(Bs + (wn*64 + ni*16 + rlo)*32 + rchunk);
#pragma unroll
    for (int mi = 0; mi < 4; ++mi)
#pragma unroll
      for (int ni = 0; ni < 4; ++ni)
        acc[mi][ni] = __builtin_amdgcn_mfma_f32_16x16x32_f16(af[mi], bf[ni], acc[mi][ni], 0, 0, 0);
  }
  int c0 = (lane >> 4) * 4;
#pragma unroll
  for (int mi = 0; mi < 4; ++mi)
#pragma unroll
    for (int ni = 0; ni < 4; ++ni)
#pragma unroll
      for (int r = 0; r < 4; ++r) {
        int row = bm*128 + wm*64 + mi*16 + c0 + r;
        int col = bn*128 + wn*64 + ni*16 + rlo;
        C[(size_t)row*SS + col] = (f16)acc[mi][ni][r];
      }
}

// ---------- K3: adjacent-row dots.  sup[s]=q[s]·k[s+1]/32,  sub[s+1]=q[s+1]·k[s]/32
__global__ __launch_bounds__(256) void k_dots(const f16* __restrict__ QK,
                                              float* __restrict__ sup,
                                              float* __restrict__ sub) {
  int pair = blockIdx.x * 4 + (threadIdx.x >> 6);   // 0..8187 (= 4*2047)
  int lane = threadIdx.x & 63;
  int b = pair / 2047;
  int s = pair - b * 2047;                          // 0..2046
  size_t r0 = ((size_t)(b*SS + s)) * SS;
  size_t r1 = r0 + SS;
  int d0 = lane * 16;
  const f16* q0 = QK + r0 + d0;
  const f16* k0 = QK + r0 + 1024 + d0;
  const f16* q1 = QK + r1 + d0;
  const f16* k1 = QK + r1 + 1024 + d0;
  float da = 0.f, dc = 0.f;
#pragma unroll
  for (int h = 0; h < 2; ++h) {
    f16x8 a  = *(const f16x8*)(q0 + h*8);
    f16x8 bk = *(const f16x8*)(k1 + h*8);
    f16x8 c  = *(const f16x8*)(q1 + h*8);
    f16x8 d  = *(const f16x8*)(k0 + h*8);
#pragma unroll
    for (int e = 0; e < 8; ++e) {
      da += (float)a[e] * (float)bk[e];
      dc += (float)c[e] * (float)d[e];
    }
  }
#pragma unroll
  for (int off = 32; off > 0; off >>= 1) {
    da += __shfl_down(da, off, 64);
    dc += __shfl_down(dc, off, 64);
  }
  if (lane == 0) {
    sup[b*SS + s]     = da * 0.03125f;
    sub[b*SS + s + 1] = dc * 0.03125f;
  }
}

// ---------- K4: per-batch probs + L + inclusive prefix sum P (double)
__global__ __launch_bounds__(1024) void k_scan(const float* __restrict__ sup,
                                               const float* __restrict__ sub,
                                               const int* __restrict__ eos,
                                               const float* __restrict__ prior,
                                               float* __restrict__ p_sup,
                                               float* __restrict__ p_sub,
                                               double* __restrict__ P) {
  int b = blockIdx.x, t = threadIdx.x;
  __shared__ float  psub_sh[SS];
  __shared__ double sc[2][1024];
  float psup_loc[2];
  size_t ebase = (size_t)b * SS * SS;
#pragma unroll
  for (int e = 0; e < 2; ++e) {
    int s = 2*t + e;
    bool supOK = (s < SS-1) && (eos[ebase + (size_t)s*SS + s + 1] != 0);
    bool subOK = (s >= 1)   && (eos[ebase + (size_t)s*SS + s - 1] != 0);
    float ps = 0.f, pb = 0.f;
    if (supOK && subOK) {
      float Av = sup[b*SS + s], Cv = sub[b*SS + s];
      float m  = fmaxf(Av, Cv);
      float ea = expf(Av - m), eb = expf(Cv - m);
      float iv = 1.0f / (ea + eb);
      ps = ea * iv; pb = eb * iv;
    } else if (supOK) ps = 1.f;
    else if (subOK)   pb = 1.f;
    p_sup[b*SS + s] = ps; p_sub[b*SS + s] = pb;
    psub_sh[s] = pb; psup_loc[e] = ps;
  }
  __syncthreads();
  double L0 = 0.0, L1 = 0.0;
#pragma unroll
  for (int e = 0; e < 2; ++e) {
    int s = 2*t + e;
    double Lv = 0.0;
    if (s < SS-1) {
      float pr = prior[ebase + (size_t)s*SS + s + 1];
      float vv = sqrtf(psup_loc[e] * psub_sh[s+1] + 1e-9f);
      Lv = (double)logf(pr + (1.f - pr)*vv + 1e-9f);
    }
    if (e == 0) L0 = Lv; else L1 = Lv;
  }
  double pairv = L0 + L1;
  int pp = 0;
  sc[0][t] = pairv;
  __syncthreads();
  for (int off = 1; off < 1024; off <<= 1) {
    double v = sc[pp][t];
    if (t >= off) v += sc[pp][t - off];
    sc[1 - pp][t] = v;
    pp ^= 1;
    __syncthreads();
  }
  double incl = sc[pp][t];
  double excl = incl - pairv;
  P[b*SS + 2*t]     = excl + L0;
  P[b*SS + 2*t + 1] = excl + L0 + L1;
}

// ---------- K5: elementwise outputs (g_attn, neibor_attn)
__global__ __launch_bounds__(256) void k_out(const float* __restrict__ prior,
                                             const float* __restrict__ p_sup,
                                             const float* __restrict__ p_sub,
                                             const double* __restrict__ P,
                                             float* __restrict__ g_out,
                                             float* __restrict__ n_out) {
  size_t v = (size_t)blockIdx.x * 256 + threadIdx.x;   // 4,194,304 threads * 4 elems
  int j4   = (int)(v & 511);
  int rowg = (int)(v >> 9);          // 0..16383
  int s = rowg & (SS - 1);
  int b = rowg >> 11;
  size_t base = (size_t)rowg * SS + j4 * 4;
  union F4 { float4 v4; float a[4]; };
  F4 prf; prf.v4 = *(const float4*)(prior + base);
  int bS = b * SS;
  double Ps  = P[bS + s];
  double Ps2 = (s >= 2) ? P[bS + s - 2] : 0.0;
  const float SQ9 = 3.1622776601683795e-5f;   // sqrt(1e-9)
  F4 gv, nv;
#pragma unroll
  for (int e = 0; e < 4; ++e) {
    int j = j4*4 + e;
    float pr = prf.a[e];
    float vv;
    if (j == s + 1)      vv = sqrtf(p_sup[bS+s] * p_sub[bS+s+1] + 1e-9f);
    else if (j == s - 1) vv = sqrtf(p_sub[bS+s] * p_sup[bS+s-1] + 1e-9f);
    else                 vv = SQ9;
    float na = pr + (1.f - pr) * vv;
    nv.a[e] = na;
    float g;
    if (s == j) g = na;
    else if (s > j) {
      double Pj2 = (j >= 2) ? P[bS + j - 2] : 0.0;
      g = expf((float)(Ps - Pj2)) + 1e-9f;
    } else {
      g = expf((float)(P[bS + j] - Ps2)) + 1e-9f;
    }
    gv.a[e] = g;
  }
  *(float4*)(g_out + base) = gv.v4;
  *(float4*)(n_out + base) = nv.v4;
}

extern "C" void kernel_launch(void* const* d_in, const int* in_sizes, int n_in,
                              void* d_out, int out_size, void* d_ws, size_t ws_size,
                              hipStream_t stream) {
  const float* context = (const float*)d_in[0];
  const int*   eos     = (const int*)d_in[1];   // jnp int64 demotes to int32 (no x64)
  const float* prior   = (const float*)d_in[2];
  const float* Wq      = (const float*)d_in[3];
  const float* Wk      = (const float*)d_in[4];
  const float* gamma   = (const float*)d_in[5];
  const float* beta    = (const float*)d_in[6];

  // small per-row arrays in ws
  char* ws = (char*)d_ws;
  float*  sup   = (float*)(ws);
  float*  sub   = (float*)(ws + 32768);
  float*  p_sup = (float*)(ws + 65536);
  float*  p_sub = (float*)(ws + 98304);
  double* P     = (double*)(ws + 131072);
  const size_t smallEnd = 196608;
  const size_t QK_BYTES = (size_t)RR * SS * 2;        // 32 MiB
  const size_t XN_BYTES = (size_t)RR * DD * 2;        // 16 MiB
  const size_t WC_BYTES = (size_t)SS * DD * 2;        //  4 MiB
  const size_t bigNeed  = QK_BYTES + XN_BYTES + WC_BYTES;
  char* big;
  if (ws_size >= smallEnd + bigNeed) big = ws + smallEnd;
  else big = (char*)d_out + ((size_t)out_size * 4 - bigNeed);  // tail of d_out; dead before k_out
  f16* QK = (f16*)big;
  f16* Xn = (f16*)(big + QK_BYTES);
  f16* Wc = (f16*)(big + QK_BYTES + XN_BYTES);

  k_wconv<<<2048, 256, 0, stream>>>(Wq, Wk, Wc);
  k_ln<<<RR, 256, 0, stream>>>(context, gamma, beta, Xn);
  k_gemm<<<1024, 256, 0, stream>>>(Xn, Wc, QK);
  k_dots<<<2047, 256, 0, stream>>>(QK, sup, sub);
  k_scan<<<4, 1024, 0, stream>>>(sup, sub, eos, prior, p_sup, p_sub, P);
  float* g_out = (float*)d_out;
  float* n_out = g_out + (size_t)RR * SS;   // 16,777,216 elems each
  k_out<<<16384, 256, 0, stream>>>(prior, p_sup, p_sub, P, g_out, n_out);
}

// Round 2
// 125.139 us; speedup vs baseline: 1.1596x; 1.1596x over previous
//
#include <hip/hip_runtime.h>
#include <hip/hip_bf16.h>
#include <stdint.h>

#define SS 2048
#define DD 1024
#define RR 8192   // B*S = 4*2048

typedef _Float16 f16;
typedef _Float16 f16x8 __attribute__((ext_vector_type(8)));
typedef _Float16 f16x4 __attribute__((ext_vector_type(4)));
typedef float    f32x4 __attribute__((ext_vector_type(4)));

// async global->LDS, 16B per lane. lptr must be wave-uniform; HW adds lane*16.
__device__ __forceinline__ void gl_lds16(const f16* g, f16* l) {
  __builtin_amdgcn_global_load_lds((const __attribute__((address_space(1))) void*)g,
                                   (__attribute__((address_space(3))) void*)l,
                                   16, 0, 0);
}

// ---------- K0: transpose Wq,Wk (f32 [1024][1024]) -> Wqt,Wkt f16 (= Wq^T, Wk^T)
__global__ __launch_bounds__(256) void k_tr(const float* __restrict__ Wq,
                                            const float* __restrict__ Wk,
                                            f16* __restrict__ Wqt,
                                            f16* __restrict__ Wkt) {
  __shared__ f16 tile[64][72];                 // 144B rows (16B-aligned stride)
  int bid = blockIdx.x;                        // 512 = 2 matrices * 16*16 tiles
  const float* src = (bid & 1) ? Wk : Wq;
  f16* dst = (bid & 1) ? Wkt : Wqt;
  int tb = bid >> 1;
  int r0 = (tb >> 4) << 6, c0 = (tb & 15) << 6;
  int t = threadIdx.x;
#pragma unroll
  for (int p = 0; p < 4; ++p) {
    int r = p * 16 + (t >> 4);
    int c = (t & 15) * 4;
    float4 v = *(const float4*)(src + (size_t)(r0 + r) * DD + c0 + c);
    tile[c + 0][r] = (f16)v.x; tile[c + 1][r] = (f16)v.y;
    tile[c + 2][r] = (f16)v.z; tile[c + 3][r] = (f16)v.w;
  }
  __syncthreads();
  int orow = t >> 2, och = (t & 3) * 16;
  f16x8 a = *(const f16x8*)&tile[orow][och];
  f16x8 b = *(const f16x8*)&tile[orow][och + 8];
  f16* o = dst + (size_t)(c0 + orow) * DD + r0 + och;
  *(f16x8*)o = a;
  *(f16x8*)(o + 8) = b;
}

// ---------- K1: LayerNorm rows of context -> f16 Xn [8192][1024]
__global__ __launch_bounds__(256) void k_ln(const float* __restrict__ x,
                                            const float* __restrict__ gamma,
                                            const float* __restrict__ beta,
                                            f16* __restrict__ xn) {
  int row = blockIdx.x;
  int tid = threadIdx.x;
  int lane = tid & 63, w = tid >> 6;
  const float* xr = x + (size_t)row * DD;
  float4 v = ((const float4*)xr)[tid];
  float s  = v.x + v.y + v.z + v.w;
  float ss = v.x*v.x + v.y*v.y + v.z*v.z + v.w*v.w;
#pragma unroll
  for (int off = 32; off > 0; off >>= 1) {
    s  += __shfl_down(s,  off, 64);
    ss += __shfl_down(ss, off, 64);
  }
  __shared__ float r0[4], r1[4];
  if (lane == 0) { r0[w] = s; r1[w] = ss; }
  __syncthreads();
  float tot = r0[0]+r0[1]+r0[2]+r0[3];
  float tss = r1[0]+r1[1]+r1[2]+r1[3];
  float mu  = tot * (1.0f/DD);
  float var = tss * (1.0f/DD) - mu*mu;
  float inv = rsqrtf(var + 1e-5f);
  float4 g = ((const float4*)gamma)[tid];
  float4 b = ((const float4*)beta)[tid];
  f16x4 o;
  o[0] = (f16)((v.x-mu)*inv*g.x + b.x);
  o[1] = (f16)((v.y-mu)*inv*g.y + b.y);
  o[2] = (f16)((v.z-mu)*inv*g.z + b.z);
  o[3] = (f16)((v.w-mu)*inv*g.w + b.w);
  *(f16x4*)(xn + (size_t)row*DD + tid*4) = o;
}

// ---------- K2: NT GEMM template  C[M][1024] = A[M][1024] @ B[1024-or-... rows][1024]^T
// f16 in, f32 acc, f16 out. K = NC = 1024 fixed. BK=32, 4 waves (2x2).
// m97 structure: global_load_lds width-16 into LINEAR LDS, 2 barriers/K-step.
template<int BM, int BN, int LOG2NBN>
__global__ __launch_bounds__(256) void k_gemm_t(const f16* __restrict__ A,
                                                const f16* __restrict__ Bw,
                                                f16* __restrict__ C) {
  constexpr int K  = 1024;
  constexpr int NC = 1024;
  constexpr int MF = BM / 32;   // frags per wave (M)
  constexpr int NF = BN / 32;   // frags per wave (N)
  constexpr int IA = BM / 64;   // A staging issues per wave
  constexpr int IB = BN / 64;
  __shared__ f16 As[BM * 32];
  __shared__ f16 Bs[BN * 32];
  int bid = blockIdx.x;
  int bm = bid >> LOG2NBN, bn = bid & ((1 << LOG2NBN) - 1);
  int tid = threadIdx.x;
  int lane = tid & 63, w = tid >> 6;
  int wm = w >> 1, wn = w & 1;

  f32x4 acc[MF][NF] = {};

  // staging: issue i covers rows [i*64, i*64+64); wave w rows +w*16..+15
  int srow = w * 16 + (lane >> 2);     // row within issue-block
  int sch  = lane & 3;                 // 16B chunk within 64B row
  const f16* AgI[IA];
  const f16* BgI[IB];
  f16* lAI[IA];
  f16* lBI[IB];
#pragma unroll
  for (int i = 0; i < IA; ++i) {
    AgI[i] = A + (size_t)(bm * BM + i * 64 + srow) * K + sch * 8;
    lAI[i] = As + (i * 64 + w * 16) * 32;
  }
#pragma unroll
  for (int i = 0; i < IB; ++i) {
    BgI[i] = Bw + (size_t)(bn * BN + i * 64 + srow) * K + sch * 8;
    lBI[i] = Bs + (i * 64 + w * 16) * 32;
  }

  int rlo = lane & 15, rch = (lane >> 4) * 8;

  for (int kt = 0; kt < K; kt += 32) {
    __syncthreads();                    // previous iteration's reads done
#pragma unroll
    for (int i = 0; i < IA; ++i) gl_lds16(AgI[i] + kt, lAI[i]);
#pragma unroll
    for (int i = 0; i < IB; ++i) gl_lds16(BgI[i] + kt, lBI[i]);
    __syncthreads();                    // vmcnt(0) drained -> tiles visible
    f16x8 af[MF], bf[NF];
#pragma unroll
    for (int mi = 0; mi < MF; ++mi)
      af[mi] = *(const f16x8*)(As + (wm * (BM/2) + mi * 16 + rlo) * 32 + rch);
#pragma unroll
    for (int ni = 0; ni < NF; ++ni)
      bf[ni] = *(const f16x8*)(Bs + (wn * (BN/2) + ni * 16 + rlo) * 32 + rch);
#pragma unroll
    for (int mi = 0; mi < MF; ++mi)
#pragma unroll
      for (int ni = 0; ni < NF; ++ni)
        acc[mi][ni] = __builtin_amdgcn_mfma_f32_16x16x32_f16(af[mi], bf[ni], acc[mi][ni], 0, 0, 0);
  }
  int c0 = (lane >> 4) * 4;
#pragma unroll
  for (int mi = 0; mi < MF; ++mi)
#pragma unroll
    for (int ni = 0; ni < NF; ++ni)
#pragma unroll
      for (int r = 0; r < 4; ++r) {
        int row = bm * BM + wm * (BM/2) + mi * 16 + c0 + r;
        int col = bn * BN + wn * (BN/2) + ni * 16 + rlo;
        C[(size_t)row * NC + col] = (f16)acc[mi][ni][r];
      }
}

// ---------- K3: adjacent-row dots + compact gathers.
// sup[s] = Xn[s]·Y[s+1]/32,  sub[s+1] = Y[s]·Xn[s+1]/32
// also: e_sup[s]=eos[s][s+1], e_sub[s+1]=eos[s+1][s], pr_sup[s]=prior[s][s+1]
__global__ __launch_bounds__(256) void k_dots(const f16* __restrict__ Xn,
                                              const f16* __restrict__ Y,
                                              const int* __restrict__ eos,
                                              const float* __restrict__ prior,
                                              float* __restrict__ sup,
                                              float* __restrict__ sub,
                                              int* __restrict__ e_sup,
                                              int* __restrict__ e_sub,
                                              float* __restrict__ pr_sup) {
  int pair = blockIdx.x * 4 + (threadIdx.x >> 6);   // 0..8187 (= 4*2047)
  int lane = threadIdx.x & 63;
  int b = pair / 2047;
  int s = pair - b * 2047;                          // 0..2046
  size_t r0 = ((size_t)(b * SS + s)) * DD;
  size_t r1 = r0 + DD;
  int d0 = lane * 16;
  float da = 0.f, dc = 0.f;
#pragma unroll
  for (int h = 0; h < 2; ++h) {
    f16x8 xs  = *(const f16x8*)(Xn + r0 + d0 + h*8);
    f16x8 ys1 = *(const f16x8*)(Y  + r1 + d0 + h*8);
    f16x8 ys  = *(const f16x8*)(Y  + r0 + d0 + h*8);
    f16x8 xs1 = *(const f16x8*)(Xn + r1 + d0 + h*8);
#pragma unroll
    for (int e = 0; e < 8; ++e) {
      da += (float)xs[e] * (float)ys1[e];
      dc += (float)ys[e] * (float)xs1[e];
    }
  }
#pragma unroll
  for (int off = 32; off > 0; off >>= 1) {
    da += __shfl_down(da, off, 64);
    dc += __shfl_down(dc, off, 64);
  }
  size_t ebase = (size_t)b * SS * SS;
  int bS = b * SS;
  if (lane == 0) {
    sup[bS + s]     = da * 0.03125f;
    sub[bS + s + 1] = dc * 0.03125f;
  } else if (lane == 1) {
    e_sup[bS + s] = eos[ebase + (size_t)s * SS + s + 1];
  } else if (lane == 2) {
    e_sub[bS + s + 1] = eos[ebase + (size_t)(s + 1) * SS + s];
  } else if (lane == 3) {
    pr_sup[bS + s] = prior[ebase + (size_t)s * SS + s + 1];
  }
}

// ---------- K4: per-batch probs + L + inclusive prefix sum P (double). Compact inputs only.
__global__ __launch_bounds__(1024) void k_scan(const float* __restrict__ sup,
                                               const float* __restrict__ sub,
                                               const int* __restrict__ e_sup,
                                               const int* __restrict__ e_sub,
                                               const float* __restrict__ pr_sup,
                                               float* __restrict__ p_sup,
                                               float* __restrict__ p_sub,
                                               double* __restrict__ P) {
  int b = blockIdx.x, t = threadIdx.x;
  int bS = b * SS;
  __shared__ float  psub_sh[SS];
  __shared__ double sc[2][1024];
  float psup_loc[2];
#pragma unroll
  for (int e = 0; e < 2; ++e) {
    int s = 2*t + e;
    bool supOK = (s < SS-1) && (e_sup[bS + s] != 0);
    bool subOK = (s >= 1)   && (e_sub[bS + s] != 0);
    float ps = 0.f, pb = 0.f;
    if (supOK && subOK) {
      float Av = sup[bS + s], Cv = sub[bS + s];
      float m  = fmaxf(Av, Cv);
      float ea = expf(Av - m), eb = expf(Cv - m);
      float iv = 1.0f / (ea + eb);
      ps = ea * iv; pb = eb * iv;
    } else if (supOK) ps = 1.f;
    else if (subOK)   pb = 1.f;
    p_sup[bS + s] = ps; p_sub[bS + s] = pb;
    psub_sh[s] = pb; psup_loc[e] = ps;
  }
  __syncthreads();
  double L0 = 0.0, L1 = 0.0;
#pragma unroll
  for (int e = 0; e < 2; ++e) {
    int s = 2*t + e;
    double Lv = 0.0;
    if (s < SS-1) {
      float pr = pr_sup[bS + s];
      float vv = sqrtf(psup_loc[e] * psub_sh[s+1] + 1e-9f);
      Lv = (double)logf(pr + (1.f - pr)*vv + 1e-9f);
    }
    if (e == 0) L0 = Lv; else L1 = Lv;
  }
  double pairv = L0 + L1;
  int pp = 0;
  sc[0][t] = pairv;
  __syncthreads();
  for (int off = 1; off < 1024; off <<= 1) {
    double v = sc[pp][t];
    if (t >= off) v += sc[pp][t - off];
    sc[1 - pp][t] = v;
    pp ^= 1;
    __syncthreads();
  }
  double incl = sc[pp][t];
  double excl = incl - pairv;
  P[bS + 2*t]     = excl + L0;
  P[bS + 2*t + 1] = excl + L0 + L1;
}

// ---------- K5: elementwise outputs (g_attn, neibor_attn)
__global__ __launch_bounds__(256) void k_out(const float* __restrict__ prior,
                                             const float* __restrict__ p_sup,
                                             const float* __restrict__ p_sub,
                                             const double* __restrict__ P,
                                             float* __restrict__ g_out,
                                             float* __restrict__ n_out) {
  size_t v = (size_t)blockIdx.x * 256 + threadIdx.x;   // 4,194,304 threads * 4 elems
  int j4   = (int)(v & 511);
  int rowg = (int)(v >> 9);          // 0..16383
  int s = rowg & (SS - 1);
  int b = rowg >> 11;
  size_t base = (size_t)rowg * SS + j4 * 4;
  union F4 { float4 v4; float a[4]; };
  F4 prf; prf.v4 = *(const float4*)(prior + base);
  int bS = b * SS;
  double Ps  = P[bS + s];
  double Ps2 = (s >= 2) ? P[bS + s - 2] : 0.0;
  const float SQ9 = 3.1622776601683795e-5f;   // sqrt(1e-9)
  F4 gv, nv;
#pragma unroll
  for (int e = 0; e < 4; ++e) {
    int j = j4*4 + e;
    float pr = prf.a[e];
    float vv;
    if (j == s + 1)      vv = sqrtf(p_sup[bS+s] * p_sub[bS+s+1] + 1e-9f);
    else if (j == s - 1) vv = sqrtf(p_sub[bS+s] * p_sup[bS+s-1] + 1e-9f);
    else                 vv = SQ9;
    float na = pr + (1.f - pr) * vv;
    nv.a[e] = na;
    float g;
    if (s == j) g = na;
    else if (s > j) {
      double Pj2 = (j >= 2) ? P[bS + j - 2] : 0.0;
      g = expf((float)(Ps - Pj2)) + 1e-9f;
    } else {
      g = expf((float)(P[bS + j] - Ps2)) + 1e-9f;
    }
    gv.a[e] = g;
  }
  *(float4*)(g_out + base) = gv.v4;
  *(float4*)(n_out + base) = nv.v4;
}

extern "C" void kernel_launch(void* const* d_in, const int* in_sizes, int n_in,
                              void* d_out, int out_size, void* d_ws, size_t ws_size,
                              hipStream_t stream) {
  const float* context = (const float*)d_in[0];
  const int*   eos     = (const int*)d_in[1];   // jnp int64 demotes to int32 (no x64)
  const float* prior   = (const float*)d_in[2];
  const float* Wq      = (const float*)d_in[3];
  const float* Wk      = (const float*)d_in[4];
  const float* gamma   = (const float*)d_in[5];
  const float* beta    = (const float*)d_in[6];

  // small per-row arrays in ws
  char* ws = (char*)d_ws;
  float*  sup    = (float*)(ws);
  float*  sub    = (float*)(ws + 32768);
  float*  p_sup  = (float*)(ws + 65536);
  float*  p_sub  = (float*)(ws + 98304);
  double* P      = (double*)(ws + 131072);         // 64 KB
  int*    e_sup  = (int*)(ws + 196608);
  int*    e_sub  = (int*)(ws + 229376);
  float*  pr_sup = (float*)(ws + 262144);
  const size_t smallEnd = 294912;

  const size_t XN_BYTES = (size_t)RR * DD * 2;     // 16 MiB
  const size_t Y_BYTES  = (size_t)RR * DD * 2;     // 16 MiB
  const size_t WT_BYTES = (size_t)DD * DD * 2;     //  2 MiB each
  const size_t bigNeed  = XN_BYTES + Y_BYTES + 3 * WT_BYTES;  // 38 MiB
  char* big;
  if (ws_size >= smallEnd + bigNeed) big = ws + smallEnd;
  else big = (char*)d_out + ((size_t)out_size * 4 - bigNeed);  // tail of d_out; dead before k_out
  f16* Xn  = (f16*)big;
  f16* Y   = (f16*)(big + XN_BYTES);
  f16* Wqt = (f16*)(big + XN_BYTES + Y_BYTES);
  f16* Wkt = (f16*)(big + XN_BYTES + Y_BYTES + WT_BYTES);
  f16* Mm  = (f16*)(big + XN_BYTES + Y_BYTES + 2 * WT_BYTES);

  k_tr<<<512, 256, 0, stream>>>(Wq, Wk, Wqt, Wkt);
  k_ln<<<RR, 256, 0, stream>>>(context, gamma, beta, Xn);
  // M = Wq^T @ Wk  ==  NT(Wqt, Wkt):  M[i][j] = sum_d Wqt[i][d]*Wkt[j][d]
  k_gemm_t<64, 64, 4><<<256, 256, 0, stream>>>(Wqt, Wkt, Mm);
  // Y = Xn @ M^T   ==  NT(Xn, M)
  k_gemm_t<128, 128, 3><<<512, 256, 0, stream>>>(Xn, Mm, Y);
  k_dots<<<2047, 256, 0, stream>>>(Xn, Y, eos, prior, sup, sub, e_sup, e_sub, pr_sup);
  k_scan<<<4, 1024, 0, stream>>>(sup, sub, e_sup, e_sub, pr_sup, p_sup, p_sub, P);
  float* g_out = (float*)d_out;
  float* n_out = g_out + (size_t)RR * SS;   // 16,777,216 elems each
  k_out<<<16384, 256, 0, stream>>>(prior, p_sup, p_sub, P, g_out, n_out);
}

// Round 3
// 120.377 us; speedup vs baseline: 1.2055x; 1.0396x over previous
//
#include <hip/hip_runtime.h>
#include <hip/hip_bf16.h>
#include <stdint.h>

#define SS 2048
#define DD 1024
#define RR 8192   // B*S = 4*2048

typedef _Float16 f16;
typedef _Float16 f16x8 __attribute__((ext_vector_type(8)));
typedef _Float16 f16x4 __attribute__((ext_vector_type(4)));
typedef float    f32x4 __attribute__((ext_vector_type(4)));

// async global->LDS, 16B per lane. lptr must be wave-uniform; HW adds lane*16.
__device__ __forceinline__ void gl_lds16(const f16* g, f16* l) {
  __builtin_amdgcn_global_load_lds((const __attribute__((address_space(1))) void*)g,
                                   (__attribute__((address_space(3))) void*)l,
                                   16, 0, 0);
}

// ---------- K1: fused  [blocks 0..RR) = LayerNorm rows -> f16 Xn,
//                       [blocks RR..RR+512) = transpose Wq,Wk (f32) -> Wqt,Wkt f16
__global__ __launch_bounds__(256) void k_pre(const float* __restrict__ x,
                                             const float* __restrict__ gamma,
                                             const float* __restrict__ beta,
                                             f16* __restrict__ xn,
                                             const float* __restrict__ Wq,
                                             const float* __restrict__ Wk,
                                             f16* __restrict__ Wqt,
                                             f16* __restrict__ Wkt) {
  __shared__ f16 tile[64][72];                 // TR: 64x64 tile, 144B rows; LN: reuses 32B
  int bidx = blockIdx.x;
  int t = threadIdx.x;
  if (bidx < RR) {
    // ---- LayerNorm row
    int lane = t & 63, w = t >> 6;
    const float* xr = x + (size_t)bidx * DD;
    float4 v = ((const float4*)xr)[t];
    float s  = v.x + v.y + v.z + v.w;
    float ss = v.x*v.x + v.y*v.y + v.z*v.z + v.w*v.w;
#pragma unroll
    for (int off = 32; off > 0; off >>= 1) {
      s  += __shfl_down(s,  off, 64);
      ss += __shfl_down(ss, off, 64);
    }
    float* r0 = (float*)&tile[0][0];
    float* r1 = r0 + 4;
    if (lane == 0) { r0[w] = s; r1[w] = ss; }
    __syncthreads();
    float tot = r0[0]+r0[1]+r0[2]+r0[3];
    float tss = r1[0]+r1[1]+r1[2]+r1[3];
    float mu  = tot * (1.0f/DD);
    float var = tss * (1.0f/DD) - mu*mu;
    float inv = rsqrtf(var + 1e-5f);
    float4 g = ((const float4*)gamma)[t];
    float4 b = ((const float4*)beta)[t];
    f16x4 o;
    o[0] = (f16)((v.x-mu)*inv*g.x + b.x);
    o[1] = (f16)((v.y-mu)*inv*g.y + b.y);
    o[2] = (f16)((v.z-mu)*inv*g.z + b.z);
    o[3] = (f16)((v.w-mu)*inv*g.w + b.w);
    *(f16x4*)(xn + (size_t)bidx*DD + t*4) = o;
  } else {
    // ---- transpose tile
    int bid = bidx - RR;                       // 0..511
    const float* src = (bid & 1) ? Wk : Wq;
    f16* dst = (bid & 1) ? Wkt : Wqt;
    int tb = bid >> 1;
    int r0 = (tb >> 4) << 6, c0 = (tb & 15) << 6;
#pragma unroll
    for (int p = 0; p < 4; ++p) {
      int r = p * 16 + (t >> 4);
      int c = (t & 15) * 4;
      float4 v = *(const float4*)(src + (size_t)(r0 + r) * DD + c0 + c);
      tile[c + 0][r] = (f16)v.x; tile[c + 1][r] = (f16)v.y;
      tile[c + 2][r] = (f16)v.z; tile[c + 3][r] = (f16)v.w;
    }
    __syncthreads();
    int orow = t >> 2, och = (t & 3) * 16;
    f16x8 a = *(const f16x8*)&tile[orow][och];
    f16x8 b = *(const f16x8*)&tile[orow][och + 8];
    f16* o = dst + (size_t)(c0 + orow) * DD + r0 + och;
    *(f16x8*)o = a;
    *(f16x8*)(o + 8) = b;
  }
}

// ---------- K2: NT GEMM template  C[M][1024] = A[..] @ B[..]^T   (f16 in, f32 acc, f16 out)
// m97 structure: global_load_lds width-16 into LINEAR LDS, 2 barriers/K-step, BK=32, 4 waves.
// XCD-aware chunked block swizzle (grid % 8 == 0).
template<int BM, int BN, int LOG2NBN>
__global__ __launch_bounds__(256) void k_gemm_t(const f16* __restrict__ A,
                                                const f16* __restrict__ Bw,
                                                f16* __restrict__ C) {
  constexpr int K  = 1024;
  constexpr int NC = 1024;
  constexpr int MF = BM / 32;
  constexpr int NF = BN / 32;
  constexpr int IA = BM / 64;
  constexpr int IB = BN / 64;
  __shared__ f16 As[BM * 32];
  __shared__ f16 Bs[BN * 32];
  int cpx = gridDim.x >> 3;                    // grid divisible by 8
  int bid = (blockIdx.x & 7) * cpx + (blockIdx.x >> 3);
  int bm = bid >> LOG2NBN, bn = bid & ((1 << LOG2NBN) - 1);
  int tid = threadIdx.x;
  int lane = tid & 63, w = tid >> 6;
  int wm = w >> 1, wn = w & 1;

  f32x4 acc[MF][NF] = {};

  int srow = w * 16 + (lane >> 2);
  int sch  = lane & 3;
  const f16* AgI[IA];
  const f16* BgI[IB];
  f16* lAI[IA];
  f16* lBI[IB];
#pragma unroll
  for (int i = 0; i < IA; ++i) {
    AgI[i] = A + (size_t)(bm * BM + i * 64 + srow) * K + sch * 8;
    lAI[i] = As + (i * 64 + w * 16) * 32;
  }
#pragma unroll
  for (int i = 0; i < IB; ++i) {
    BgI[i] = Bw + (size_t)(bn * BN + i * 64 + srow) * K + sch * 8;
    lBI[i] = Bs + (i * 64 + w * 16) * 32;
  }

  int rlo = lane & 15, rch = (lane >> 4) * 8;

  for (int kt = 0; kt < K; kt += 32) {
    __syncthreads();
#pragma unroll
    for (int i = 0; i < IA; ++i) gl_lds16(AgI[i] + kt, lAI[i]);
#pragma unroll
    for (int i = 0; i < IB; ++i) gl_lds16(BgI[i] + kt, lBI[i]);
    __syncthreads();
    f16x8 af[MF], bf[NF];
#pragma unroll
    for (int mi = 0; mi < MF; ++mi)
      af[mi] = *(const f16x8*)(As + (wm * (BM/2) + mi * 16 + rlo) * 32 + rch);
#pragma unroll
    for (int ni = 0; ni < NF; ++ni)
      bf[ni] = *(const f16x8*)(Bs + (wn * (BN/2) + ni * 16 + rlo) * 32 + rch);
#pragma unroll
    for (int mi = 0; mi < MF; ++mi)
#pragma unroll
      for (int ni = 0; ni < NF; ++ni)
        acc[mi][ni] = __builtin_amdgcn_mfma_f32_16x16x32_f16(af[mi], bf[ni], acc[mi][ni], 0, 0, 0);
  }
  int c0 = (lane >> 4) * 4;
#pragma unroll
  for (int mi = 0; mi < MF; ++mi)
#pragma unroll
    for (int ni = 0; ni < NF; ++ni)
#pragma unroll
      for (int r = 0; r < 4; ++r) {
        int row = bm * BM + wm * (BM/2) + mi * 16 + c0 + r;
        int col = bn * BN + wn * (BN/2) + ni * 16 + rlo;
        C[(size_t)row * NC + col] = (f16)acc[mi][ni][r];
      }
}

// ---------- K3: adjacent-row dots + compact gathers (XCD-chunked for L2 row reuse)
__global__ __launch_bounds__(256) void k_dots(const f16* __restrict__ Xn,
                                              const f16* __restrict__ Y,
                                              const int* __restrict__ eos,
                                              const float* __restrict__ prior,
                                              float* __restrict__ sup,
                                              float* __restrict__ sub,
                                              int* __restrict__ e_sup,
                                              int* __restrict__ e_sub,
                                              float* __restrict__ pr_sup) {
  // bijective XCD swizzle for nwg=2047 (q=255, r=7)
  int q = (int)gridDim.x >> 3, r7 = (int)gridDim.x & 7;
  int xcd = blockIdx.x & 7, idx = blockIdx.x >> 3;
  int sb = (xcd < r7 ? xcd * (q + 1) : r7 * (q + 1) + (xcd - r7) * q) + idx;
  int pair = sb * 4 + (threadIdx.x >> 6);           // 0..8187 (= 4*2047)
  int lane = threadIdx.x & 63;
  int b = pair / 2047;
  int s = pair - b * 2047;                          // 0..2046
  size_t r0 = ((size_t)(b * SS + s)) * DD;
  size_t r1 = r0 + DD;
  int d0 = lane * 16;
  float da = 0.f, dc = 0.f;
#pragma unroll
  for (int h = 0; h < 2; ++h) {
    f16x8 xs  = *(const f16x8*)(Xn + r0 + d0 + h*8);
    f16x8 ys1 = *(const f16x8*)(Y  + r1 + d0 + h*8);
    f16x8 ys  = *(const f16x8*)(Y  + r0 + d0 + h*8);
    f16x8 xs1 = *(const f16x8*)(Xn + r1 + d0 + h*8);
#pragma unroll
    for (int e = 0; e < 8; ++e) {
      da += (float)xs[e] * (float)ys1[e];
      dc += (float)ys[e] * (float)xs1[e];
    }
  }
#pragma unroll
  for (int off = 32; off > 0; off >>= 1) {
    da += __shfl_down(da, off, 64);
    dc += __shfl_down(dc, off, 64);
  }
  size_t ebase = (size_t)b * SS * SS;
  int bS = b * SS;
  if (lane == 0) {
    sup[bS + s]     = da * 0.03125f;
    sub[bS + s + 1] = dc * 0.03125f;
  } else if (lane == 1) {
    e_sup[bS + s] = eos[ebase + (size_t)s * SS + s + 1];
  } else if (lane == 2) {
    e_sub[bS + s + 1] = eos[ebase + (size_t)(s + 1) * SS + s];
  } else if (lane == 3) {
    pr_sup[bS + s] = prior[ebase + (size_t)s * SS + s + 1];
  }
}

// ---------- K4: per-batch probs + L + inclusive prefix sum P (double), shuffle scan
__global__ __launch_bounds__(1024) void k_scan(const float* __restrict__ sup,
                                               const float* __restrict__ sub,
                                               const int* __restrict__ e_sup,
                                               const int* __restrict__ e_sub,
                                               const float* __restrict__ pr_sup,
                                               float* __restrict__ p_sup,
                                               float* __restrict__ p_sub,
                                               double* __restrict__ P) {
  int b = blockIdx.x, t = threadIdx.x;
  int lane = t & 63, wid = t >> 6;
  int bS = b * SS;
  __shared__ float  psub_sh[SS];
  __shared__ double wsum[16];
  float psup_loc[2];
#pragma unroll
  for (int e = 0; e < 2; ++e) {
    int s = 2*t + e;
    bool supOK = (s < SS-1) && (e_sup[bS + s] != 0);
    bool subOK = (s >= 1)   && (e_sub[bS + s] != 0);
    float ps = 0.f, pb = 0.f;
    if (supOK && subOK) {
      float Av = sup[bS + s], Cv = sub[bS + s];
      float m  = fmaxf(Av, Cv);
      float ea = expf(Av - m), eb = expf(Cv - m);
      float iv = 1.0f / (ea + eb);
      ps = ea * iv; pb = eb * iv;
    } else if (supOK) ps = 1.f;
    else if (subOK)   pb = 1.f;
    p_sup[bS + s] = ps; p_sub[bS + s] = pb;
    psub_sh[s] = pb; psup_loc[e] = ps;
  }
  __syncthreads();
  double L0 = 0.0, L1 = 0.0;
#pragma unroll
  for (int e = 0; e < 2; ++e) {
    int s = 2*t + e;
    double Lv = 0.0;
    if (s < SS-1) {
      float pr = pr_sup[bS + s];
      float vv = sqrtf(psup_loc[e] * psub_sh[s+1] + 1e-9f);
      Lv = (double)logf(pr + (1.f - pr)*vv + 1e-9f);
    }
    if (e == 0) L0 = Lv; else L1 = Lv;
  }
  double pairv = L0 + L1;
  // wave-level inclusive scan (no barriers)
  double v = pairv;
#pragma unroll
  for (int off = 1; off < 64; off <<= 1) {
    double u = __shfl_up(v, off, 64);
    if (lane >= off) v += u;
  }
  if (lane == 63) wsum[wid] = v;
  __syncthreads();
  double base = 0.0;
  for (int wI = 0; wI < wid; ++wI) base += wsum[wI];   // broadcast LDS reads, <=15 iters
  double excl = base + v - pairv;
  P[bS + 2*t]     = excl + L0;
  P[bS + 2*t + 1] = excl + L0 + L1;
}

// ---------- K5: elementwise outputs (g_attn, neibor_attn)
__global__ __launch_bounds__(256) void k_out(const float* __restrict__ prior,
                                             const float* __restrict__ p_sup,
                                             const float* __restrict__ p_sub,
                                             const double* __restrict__ P,
                                             float* __restrict__ g_out,
                                             float* __restrict__ n_out) {
  size_t v = (size_t)blockIdx.x * 256 + threadIdx.x;   // 4,194,304 threads * 4 elems
  int j4   = (int)(v & 511);
  int rowg = (int)(v >> 9);          // 0..16383
  int s = rowg & (SS - 1);
  int b = rowg >> 11;
  size_t base = (size_t)rowg * SS + j4 * 4;
  union F4 { float4 v4; float a[4]; };
  F4 prf; prf.v4 = *(const float4*)(prior + base);
  int bS = b * SS;
  double Ps  = P[bS + s];
  double Ps2 = (s >= 2) ? P[bS + s - 2] : 0.0;
  const float SQ9 = 3.1622776601683795e-5f;   // sqrt(1e-9)
  F4 gv, nv;
#pragma unroll
  for (int e = 0; e < 4; ++e) {
    int j = j4*4 + e;
    float pr = prf.a[e];
    float vv;
    if (j == s + 1)      vv = sqrtf(p_sup[bS+s] * p_sub[bS+s+1] + 1e-9f);
    else if (j == s - 1) vv = sqrtf(p_sub[bS+s] * p_sup[bS+s-1] + 1e-9f);
    else                 vv = SQ9;
    float na = pr + (1.f - pr) * vv;
    nv.a[e] = na;
    float g;
    if (s == j) g = na;
    else if (s > j) {
      double Pj2 = (j >= 2) ? P[bS + j - 2] : 0.0;
      g = expf((float)(Ps - Pj2)) + 1e-9f;
    } else {
      g = expf((float)(P[bS + j] - Ps2)) + 1e-9f;
    }
    gv.a[e] = g;
  }
  *(float4*)(g_out + base) = gv.v4;
  *(float4*)(n_out + base) = nv.v4;
}

extern "C" void kernel_launch(void* const* d_in, const int* in_sizes, int n_in,
                              void* d_out, int out_size, void* d_ws, size_t ws_size,
                              hipStream_t stream) {
  const float* context = (const float*)d_in[0];
  const int*   eos     = (const int*)d_in[1];   // jnp int64 demotes to int32 (no x64)
  const float* prior   = (const float*)d_in[2];
  const float* Wq      = (const float*)d_in[3];
  const float* Wk      = (const float*)d_in[4];
  const float* gamma   = (const float*)d_in[5];
  const float* beta    = (const float*)d_in[6];

  // small per-row arrays in ws
  char* ws = (char*)d_ws;
  float*  sup    = (float*)(ws);
  float*  sub    = (float*)(ws + 32768);
  float*  p_sup  = (float*)(ws + 65536);
  float*  p_sub  = (float*)(ws + 98304);
  double* P      = (double*)(ws + 131072);         // 64 KB
  int*    e_sup  = (int*)(ws + 196608);
  int*    e_sub  = (int*)(ws + 229376);
  float*  pr_sup = (float*)(ws + 262144);
  const size_t smallEnd = 294912;

  const size_t XN_BYTES = (size_t)RR * DD * 2;     // 16 MiB
  const size_t Y_BYTES  = (size_t)RR * DD * 2;     // 16 MiB
  const size_t WT_BYTES = (size_t)DD * DD * 2;     //  2 MiB each
  const size_t bigNeed  = XN_BYTES + Y_BYTES + 3 * WT_BYTES;  // 38 MiB
  char* big;
  if (ws_size >= smallEnd + bigNeed) big = ws + smallEnd;
  else big = (char*)d_out + ((size_t)out_size * 4 - bigNeed);  // tail of d_out; dead before k_out
  f16* Xn  = (f16*)big;
  f16* Y   = (f16*)(big + XN_BYTES);
  f16* Wqt = (f16*)(big + XN_BYTES + Y_BYTES);
  f16* Wkt = (f16*)(big + XN_BYTES + Y_BYTES + WT_BYTES);
  f16* Mm  = (f16*)(big + XN_BYTES + Y_BYTES + 2 * WT_BYTES);

  k_pre<<<RR + 512, 256, 0, stream>>>(context, gamma, beta, Xn, Wq, Wk, Wqt, Wkt);
  // M = Wq^T @ Wk  ==  NT(Wqt, Wkt)
  k_gemm_t<64, 64, 4><<<256, 256, 0, stream>>>(Wqt, Wkt, Mm);
  // Y = Xn @ M^T   ==  NT(Xn, M)
  k_gemm_t<128, 128, 3><<<512, 256, 0, stream>>>(Xn, Mm, Y);
  k_dots<<<2047, 256, 0, stream>>>(Xn, Y, eos, prior, sup, sub, e_sup, e_sub, pr_sup);
  k_scan<<<4, 1024, 0, stream>>>(sup, sub, e_sup, e_sub, pr_sup, p_sup, p_sub, P);
  float* g_out = (float*)d_out;
  float* n_out = g_out + (size_t)RR * SS;   // 16,777,216 elems each
  k_out<<<16384, 256, 0, stream>>>(prior, p_sup, p_sub, P, g_out, n_out);
}

// Round 4
// 103.369 us; speedup vs baseline: 1.4038x; 1.1645x over previous
//
#include <hip/hip_runtime.h>
#include <hip/hip_bf16.h>
#include <stdint.h>

#define SS 2048
#define DD 1024
#define RR 8192   // B*S = 4*2048

typedef _Float16 f16;
typedef _Float16 f16x8 __attribute__((ext_vector_type(8)));
typedef _Float16 f16x4 __attribute__((ext_vector_type(4)));
typedef float    f32x4 __attribute__((ext_vector_type(4)));

// async global->LDS, 16B per lane. lptr must be wave-uniform; HW adds lane*16.
__device__ __forceinline__ void gl_lds16(const f16* g, f16* l) {
  __builtin_amdgcn_global_load_lds((const __attribute__((address_space(1))) void*)g,
                                   (__attribute__((address_space(3))) void*)l,
                                   16, 0, 0);
}

// ---------- K1: fused prologue
//   blocks [0, RR)            : LayerNorm rows -> f16 Xn
//   blocks [RR, RR+512)       : transpose Wq,Wk (f32) -> Wqt,Wkt f16
//   blocks [RR+512, RR+544)   : diag gathers (eos, prior) + zero sup_g/sub_g
__global__ __launch_bounds__(256) void k_pre(const float* __restrict__ x,
                                             const float* __restrict__ gamma,
                                             const float* __restrict__ beta,
                                             f16* __restrict__ xn,
                                             const float* __restrict__ Wq,
                                             const float* __restrict__ Wk,
                                             f16* __restrict__ Wqt,
                                             f16* __restrict__ Wkt,
                                             const int* __restrict__ eos,
                                             const float* __restrict__ prior,
                                             float* __restrict__ sup_g,
                                             float* __restrict__ sub_g,
                                             int* __restrict__ e_sup,
                                             int* __restrict__ e_sub,
                                             float* __restrict__ pr_sup) {
  __shared__ f16 tile[64][72];
  int bidx = blockIdx.x;
  int t = threadIdx.x;
  if (bidx < RR) {
    // ---- LayerNorm row
    int lane = t & 63, w = t >> 6;
    const float* xr = x + (size_t)bidx * DD;
    float4 v = ((const float4*)xr)[t];
    float s  = v.x + v.y + v.z + v.w;
    float ss = v.x*v.x + v.y*v.y + v.z*v.z + v.w*v.w;
#pragma unroll
    for (int off = 32; off > 0; off >>= 1) {
      s  += __shfl_down(s,  off, 64);
      ss += __shfl_down(ss, off, 64);
    }
    float* r0 = (float*)&tile[0][0];
    float* r1 = r0 + 4;
    if (lane == 0) { r0[w] = s; r1[w] = ss; }
    __syncthreads();
    float tot = r0[0]+r0[1]+r0[2]+r0[3];
    float tss = r1[0]+r1[1]+r1[2]+r1[3];
    float mu  = tot * (1.0f/DD);
    float var = tss * (1.0f/DD) - mu*mu;
    float inv = rsqrtf(var + 1e-5f);
    float4 g = ((const float4*)gamma)[t];
    float4 b = ((const float4*)beta)[t];
    f16x4 o;
    o[0] = (f16)((v.x-mu)*inv*g.x + b.x);
    o[1] = (f16)((v.y-mu)*inv*g.y + b.y);
    o[2] = (f16)((v.z-mu)*inv*g.z + b.z);
    o[3] = (f16)((v.w-mu)*inv*g.w + b.w);
    *(f16x4*)(xn + (size_t)bidx*DD + t*4) = o;
  } else if (bidx < RR + 512) {
    // ---- transpose tile
    int bid = bidx - RR;                       // 0..511
    const float* src = (bid & 1) ? Wk : Wq;
    f16* dst = (bid & 1) ? Wkt : Wqt;
    int tb = bid >> 1;
    int r0 = (tb >> 4) << 6, c0 = (tb & 15) << 6;
#pragma unroll
    for (int p = 0; p < 4; ++p) {
      int r = p * 16 + (t >> 4);
      int c = (t & 15) * 4;
      float4 v = *(const float4*)(src + (size_t)(r0 + r) * DD + c0 + c);
      tile[c + 0][r] = (f16)v.x; tile[c + 1][r] = (f16)v.y;
      tile[c + 2][r] = (f16)v.z; tile[c + 3][r] = (f16)v.w;
    }
    __syncthreads();
    int orow = t >> 2, och = (t & 3) * 16;
    f16x8 a = *(const f16x8*)&tile[orow][och];
    f16x8 b = *(const f16x8*)&tile[orow][och + 8];
    f16* o = dst + (size_t)(c0 + orow) * DD + r0 + och;
    *(f16x8*)o = a;
    *(f16x8*)(o + 8) = b;
  } else {
    // ---- gathers + zero accumulators
    int g = bidx - (RR + 512);                 // 0..31
    int u = g * 256 + t;                       // 0..8191
    sup_g[u] = 0.f;
    sub_g[u] = 0.f;
    if (u < 4 * 2047) {
      int b = u / 2047;
      int s = u - b * 2047;                    // 0..2046
      size_t ebase = (size_t)b * SS * SS;
      int bS = b * SS;
      e_sup[bS + s]     = eos[ebase + (size_t)s * SS + s + 1];
      e_sub[bS + s + 1] = eos[ebase + (size_t)(s + 1) * SS + s];
      pr_sup[bS + s]    = prior[ebase + (size_t)s * SS + s + 1];
    }
  }
}

// ---------- K2: NT GEMM template  C = A @ B^T   (f16 in, f32 acc)
// m97 structure: global_load_lds width-16 into LINEAR LDS, 2 barriers/K-step, BK=32, 4 waves.
// FUSE=true: no C write; instead compute adjacent-row dots against A (=Xn) and
// atomicAdd scaled partials into sup_g/sub_g.
template<int BM, int BN, int LOG2NBN, bool FUSE>
__global__ __launch_bounds__(256) void k_gemm_t(const f16* __restrict__ A,
                                                const f16* __restrict__ Bw,
                                                f16* __restrict__ C,
                                                float* __restrict__ sup_g,
                                                float* __restrict__ sub_g) {
  constexpr int K  = 1024;
  constexpr int NC = 1024;
  constexpr int MF = BM / 32;
  constexpr int NF = BN / 32;
  constexpr int IA = BM / 64;
  constexpr int IB = BN / 64;
  constexpr int XST = 136;                     // slab stride (f16): 16B-aligned, 4-way max
  __shared__ f16 As[BM * 32];
  __shared__ f16 Bs[BN * 32];
  __shared__ f16 Xs[FUSE ? 130 * XST : 1];
  int cpx = gridDim.x >> 3;                    // grid divisible by 8
  int bid = (blockIdx.x & 7) * cpx + (blockIdx.x >> 3);
  int bm = bid >> LOG2NBN, bn = bid & ((1 << LOG2NBN) - 1);
  int tid = threadIdx.x;
  int lane = tid & 63, w = tid >> 6;
  int wm = w >> 1, wn = w & 1;

  f32x4 acc[MF][NF] = {};

  int srow = w * 16 + (lane >> 2);
  int sch  = lane & 3;
  const f16* AgI[IA];
  const f16* BgI[IB];
  f16* lAI[IA];
  f16* lBI[IB];
#pragma unroll
  for (int i = 0; i < IA; ++i) {
    AgI[i] = A + (size_t)(bm * BM + i * 64 + srow) * K + sch * 8;
    lAI[i] = As + (i * 64 + w * 16) * 32;
  }
#pragma unroll
  for (int i = 0; i < IB; ++i) {
    BgI[i] = Bw + (size_t)(bn * BN + i * 64 + srow) * K + sch * 8;
    lBI[i] = Bs + (i * 64 + w * 16) * 32;
  }

  int rlo = lane & 15, rch = (lane >> 4) * 8;

  for (int kt = 0; kt < K; kt += 32) {
    __syncthreads();
#pragma unroll
    for (int i = 0; i < IA; ++i) gl_lds16(AgI[i] + kt, lAI[i]);
#pragma unroll
    for (int i = 0; i < IB; ++i) gl_lds16(BgI[i] + kt, lBI[i]);
    __syncthreads();
    f16x8 af[MF], bf[NF];
#pragma unroll
    for (int mi = 0; mi < MF; ++mi)
      af[mi] = *(const f16x8*)(As + (wm * (BM/2) + mi * 16 + rlo) * 32 + rch);
#pragma unroll
    for (int ni = 0; ni < NF; ++ni)
      bf[ni] = *(const f16x8*)(Bs + (wn * (BN/2) + ni * 16 + rlo) * 32 + rch);
#pragma unroll
    for (int mi = 0; mi < MF; ++mi)
#pragma unroll
      for (int ni = 0; ni < NF; ++ni)
        acc[mi][ni] = __builtin_amdgcn_mfma_f32_16x16x32_f16(af[mi], bf[ni], acc[mi][ni], 0, 0, 0);
  }
  int c0 = (lane >> 4) * 4;
  if constexpr (!FUSE) {
#pragma unroll
    for (int mi = 0; mi < MF; ++mi)
#pragma unroll
      for (int ni = 0; ni < NF; ++ni)
#pragma unroll
        for (int r = 0; r < 4; ++r) {
          int row = bm * BM + wm * (BM/2) + mi * 16 + c0 + r;
          int col = bn * BN + wn * (BN/2) + ni * 16 + rlo;
          C[(size_t)row * NC + col] = (f16)acc[mi][ni][r];
        }
  } else {
    // ---- fused adjacent-row dot epilogue.
    // Y[rho][col] lives in acc: rho = bm*128 + wm*64 + mi*16 + c0 + r,
    //                           col = bn*128 + wn*64 + ni*16 + rlo.
    // sup_g[rho-1] += Y[rho]·Xn[rho-1] /32 ; sub_g[rho+1] += Y[rho]·Xn[rho+1] /32.
    // Stage Xn rows [bm*128-1, bm*128+128] x cols [bn*128, +128) into Xs.
    int slabBase = bm * BM - 1;
#pragma unroll
    for (int it = 0; it < 9; ++it) {
      int c = tid + it * 256;                  // chunk id over 130*16
      if (c < 130 * 16) {
        int rI = c >> 4, colc = (c & 15) * 8;
        int gr = slabBase + rI;
        gr = gr < 0 ? 0 : (gr > RR - 1 ? RR - 1 : gr);
        *(f16x8*)(Xs + rI * XST + colc) =
            *(const f16x8*)(A + (size_t)gr * K + bn * BN + colc);
      }
    }
    __syncthreads();
#pragma unroll
    for (int mi = 0; mi < MF; ++mi) {
#pragma unroll
      for (int r = 0; r < 4; ++r) {
        int rloc = wm * (BM/2) + mi * 16 + c0 + r;   // rho - bm*BM
        float su = 0.f, sb = 0.f;
#pragma unroll
        for (int ni = 0; ni < NF; ++ni) {
          float y = acc[mi][ni][r];
          int colL = wn * (BN/2) + ni * 16 + rlo;
          su += y * (float)Xs[rloc * XST + colL];        // row (rho-1)-slabBase = rloc
          sb += y * (float)Xs[(rloc + 2) * XST + colL];  // row (rho+1)-slabBase
        }
#pragma unroll
        for (int m = 1; m < 16; m <<= 1) {
          su += __shfl_xor(su, m, 64);
          sb += __shfl_xor(sb, m, 64);
        }
        if (rlo == 0) {
          int rho = bm * BM + rloc;
          if ((rho & (SS - 1)) != 0)
            atomicAdd(&sup_g[rho - 1], su * 0.03125f);
          if ((rho & (SS - 1)) != SS - 1)
            atomicAdd(&sub_g[rho + 1], sb * 0.03125f);
        }
      }
    }
  }
}

// ---------- K4: per-batch probs + L + inclusive prefix sum P (double), shuffle scan
__global__ __launch_bounds__(1024) void k_scan(const float* __restrict__ sup,
                                               const float* __restrict__ sub,
                                               const int* __restrict__ e_sup,
                                               const int* __restrict__ e_sub,
                                               const float* __restrict__ pr_sup,
                                               float* __restrict__ p_sup,
                                               float* __restrict__ p_sub,
                                               double* __restrict__ P) {
  int b = blockIdx.x, t = threadIdx.x;
  int lane = t & 63, wid = t >> 6;
  int bS = b * SS;
  __shared__ float  psub_sh[SS];
  __shared__ double wsum[16];
  float psup_loc[2];
#pragma unroll
  for (int e = 0; e < 2; ++e) {
    int s = 2*t + e;
    bool supOK = (s < SS-1) && (e_sup[bS + s] != 0);
    bool subOK = (s >= 1)   && (e_sub[bS + s] != 0);
    float ps = 0.f, pb = 0.f;
    if (supOK && subOK) {
      float Av = sup[bS + s], Cv = sub[bS + s];
      float m  = fmaxf(Av, Cv);
      float ea = expf(Av - m), eb = expf(Cv - m);
      float iv = 1.0f / (ea + eb);
      ps = ea * iv; pb = eb * iv;
    } else if (supOK) ps = 1.f;
    else if (subOK)   pb = 1.f;
    p_sup[bS + s] = ps; p_sub[bS + s] = pb;
    psub_sh[s] = pb; psup_loc[e] = ps;
  }
  __syncthreads();
  double L0 = 0.0, L1 = 0.0;
#pragma unroll
  for (int e = 0; e < 2; ++e) {
    int s = 2*t + e;
    double Lv = 0.0;
    if (s < SS-1) {
      float pr = pr_sup[bS + s];
      float vv = sqrtf(psup_loc[e] * psub_sh[s+1] + 1e-9f);
      Lv = (double)logf(pr + (1.f - pr)*vv + 1e-9f);
    }
    if (e == 0) L0 = Lv; else L1 = Lv;
  }
  double pairv = L0 + L1;
  double v = pairv;
#pragma unroll
  for (int off = 1; off < 64; off <<= 1) {
    double u = __shfl_up(v, off, 64);
    if (lane >= off) v += u;
  }
  if (lane == 63) wsum[wid] = v;
  __syncthreads();
  double base = 0.0;
  for (int wI = 0; wI < wid; ++wI) base += wsum[wI];
  double excl = base + v - pairv;
  P[bS + 2*t]     = excl + L0;
  P[bS + 2*t + 1] = excl + L0 + L1;
}

// ---------- K5: elementwise outputs (g_attn, neibor_attn)
__global__ __launch_bounds__(256) void k_out(const float* __restrict__ prior,
                                             const float* __restrict__ p_sup,
                                             const float* __restrict__ p_sub,
                                             const double* __restrict__ P,
                                             float* __restrict__ g_out,
                                             float* __restrict__ n_out) {
  size_t v = (size_t)blockIdx.x * 256 + threadIdx.x;
  int j4   = (int)(v & 511);
  int rowg = (int)(v >> 9);          // 0..16383
  int s = rowg & (SS - 1);
  int b = rowg >> 11;
  size_t base = (size_t)rowg * SS + j4 * 4;
  union F4 { float4 v4; float a[4]; };
  F4 prf; prf.v4 = *(const float4*)(prior + base);
  int bS = b * SS;
  double Ps  = P[bS + s];
  double Ps2 = (s >= 2) ? P[bS + s - 2] : 0.0;
  const float SQ9 = 3.1622776601683795e-5f;   // sqrt(1e-9)
  F4 gv, nv;
#pragma unroll
  for (int e = 0; e < 4; ++e) {
    int j = j4*4 + e;
    float pr = prf.a[e];
    float vv;
    if (j == s + 1)      vv = sqrtf(p_sup[bS+s] * p_sub[bS+s+1] + 1e-9f);
    else if (j == s - 1) vv = sqrtf(p_sub[bS+s] * p_sup[bS+s-1] + 1e-9f);
    else                 vv = SQ9;
    float na = pr + (1.f - pr) * vv;
    nv.a[e] = na;
    float g;
    if (s == j) g = na;
    else if (s > j) {
      double Pj2 = (j >= 2) ? P[bS + j - 2] : 0.0;
      g = expf((float)(Ps - Pj2)) + 1e-9f;
    } else {
      g = expf((float)(P[bS + j] - Ps2)) + 1e-9f;
    }
    gv.a[e] = g;
  }
  *(float4*)(g_out + base) = gv.v4;
  *(float4*)(n_out + base) = nv.v4;
}

extern "C" void kernel_launch(void* const* d_in, const int* in_sizes, int n_in,
                              void* d_out, int out_size, void* d_ws, size_t ws_size,
                              hipStream_t stream) {
  const float* context = (const float*)d_in[0];
  const int*   eos     = (const int*)d_in[1];   // jnp int64 demotes to int32 (no x64)
  const float* prior   = (const float*)d_in[2];
  const float* Wq      = (const float*)d_in[3];
  const float* Wk      = (const float*)d_in[4];
  const float* gamma   = (const float*)d_in[5];
  const float* beta    = (const float*)d_in[6];

  char* ws = (char*)d_ws;
  float*  sup    = (float*)(ws);
  float*  sub    = (float*)(ws + 32768);
  float*  p_sup  = (float*)(ws + 65536);
  float*  p_sub  = (float*)(ws + 98304);
  double* P      = (double*)(ws + 131072);         // 64 KB
  int*    e_sup  = (int*)(ws + 196608);
  int*    e_sub  = (int*)(ws + 229376);
  float*  pr_sup = (float*)(ws + 262144);
  const size_t smallEnd = 294912;

  const size_t XN_BYTES = (size_t)RR * DD * 2;     // 16 MiB
  const size_t WT_BYTES = (size_t)DD * DD * 2;     //  2 MiB each
  const size_t bigNeed  = XN_BYTES + 3 * WT_BYTES; // 22 MiB
  char* big;
  if (ws_size >= smallEnd + bigNeed) big = ws + smallEnd;
  else big = (char*)d_out + ((size_t)out_size * 4 - bigNeed);  // tail of d_out; dead before k_out
  f16* Xn  = (f16*)big;
  f16* Wqt = (f16*)(big + XN_BYTES);
  f16* Wkt = (f16*)(big + XN_BYTES + WT_BYTES);
  f16* Mm  = (f16*)(big + XN_BYTES + 2 * WT_BYTES);

  k_pre<<<RR + 512 + 32, 256, 0, stream>>>(context, gamma, beta, Xn, Wq, Wk, Wqt, Wkt,
                                           eos, prior, sup, sub, e_sup, e_sub, pr_sup);
  // M = Wq^T @ Wk  ==  NT(Wqt, Wkt)
  k_gemm_t<64, 64, 4, false><<<256, 256, 0, stream>>>(Wqt, Wkt, Mm, nullptr, nullptr);
  // Y = Xn @ M^T fused with adjacent-row dots -> sup/sub (atomic)
  k_gemm_t<128, 128, 3, true><<<512, 256, 0, stream>>>(Xn, Mm, nullptr, sup, sub);
  k_scan<<<4, 1024, 0, stream>>>(sup, sub, e_sup, e_sub, pr_sup, p_sup, p_sub, P);
  float* g_out = (float*)d_out;
  float* n_out = g_out + (size_t)RR * SS;   // 16,777,216 elems each
  k_out<<<16384, 256, 0, stream>>>(prior, p_sup, p_sub, P, g_out, n_out);
}